// Round 8
// baseline (351.934 us; speedup 1.0000x reference)
//
#include <hip/hip_runtime.h>

#define D_MODEL 512
#define D_FF    2048
#define NEXP    8
#define TOKENS  8192
#define TROWS   26368     // 8192 universal + <=18176 expert slots padded to 256

typedef __bf16 bf16_t;
typedef __attribute__((ext_vector_type(8))) __bf16 bf16x8_t;
typedef __attribute__((ext_vector_type(4))) __bf16 bf16x4_t;
typedef __attribute__((ext_vector_type(4))) float  f32x4_t;

// ---- workspace layout (bytes) ----
#define W1P_OFF    0u            // bf16 [16][2048][32] x8 experts
#define UW1P_OFF   16777216u     // bf16 [16][2048][32]
#define W2P_OFF    18874368u     // bf16 [64][512][32] x8
#define UW2P_OFF   35651584u     // bf16 [64][512][32]
#define CNT_OFF    37748736u     // int[16]
#define TOKL_OFF   37748800u     // int  [8][8192]
#define GATEL_OFF  38010944u     // float[8][8192]
#define OMEGA_OFF  38273088u     // float[8192]
#define TLOG_OFF   38305856u     // double[8][8]
#define SOFF_OFF   38306368u     // int[16]
#define RMETA_OFF  38306496u     // int[TROWS]
#define RGATE_OFF  38411968u     // float[TROWS]
#define XGP_OFF    38517440u     // bf16 [16][TROWS][32]
#define S0_OFF     38517440u     // ALIAS of XGP (xgp dead before gemm2 writes s0/s1)
#define S1_OFF     46906048u     // ALIAS of XGP
#define HP_OFF     65517248u     // bf16 [64][TROWS][32]
#define TOKE_OFF   173516480u    // int[8192]
#define TG_OFF     173549248u    // float2[8192]
#define TMAP_OFF   173614784u    // int[136]

__device__ inline f32x4_t mfma_bf16(bf16x8_t a, bf16x8_t b, f32x4_t c) {
  return __builtin_amdgcn_mfma_f32_16x16x32_bf16(a, b, c, 0, 0, 0);
}

__device__ __forceinline__ void load_lds16(const void* g, void* l) {
  __builtin_amdgcn_global_load_lds(
      (const __attribute__((address_space(1))) unsigned int*)g,
      (__attribute__((address_space(3))) unsigned int*)l, 16, 0, 0);
}

// fast gelu: max abs err ~3e-4 << bf16 quantum
__device__ __forceinline__ float fast_gelu(float x) {
  float z = 0.7978845608f * (x + 0.044715f * x * x * x);
  float u = __expf(2.0f * z);
  float th = (u - 1.0f) * __builtin_amdgcn_rcpf(u + 1.0f);
  return 0.5f * x * (1.0f + th);
}

// pack in[R][C] f32 -> out[R/32][C][32] bf16, LDS-free; z==8 selects universal
__global__ void k_pack(const float* __restrict__ wE, const float* __restrict__ wU,
                       bf16_t* __restrict__ oE, bf16_t* __restrict__ oU, int R, int C) {
  const int z = blockIdx.z;
  const float* in = (z < 8) ? wE + (size_t)z * R * C : wU;
  bf16_t* out     = (z < 8) ? oE + (size_t)z * R * C : oU;
  int r0 = blockIdx.y * 64, c0 = blockIdx.x * 64;
  int item = threadIdx.x >> 1, jh = threadIdx.x & 1;
  int c = item & 63, s = item >> 6;
  const float* src = in + (size_t)(r0 + s * 32 + jh * 16) * C + (c0 + c);
  union { bf16_t h[16]; uint4 u[2]; } t;
#pragma unroll
  for (int k = 0; k < 16; k++) t.h[k] = (bf16_t)src[(size_t)k * C];
  char* dst = (char*)out + ((size_t)((r0 >> 5) + s) * C + (c0 + c)) * 64 + jh * 32;
  ((uint4*)dst)[0] = t.u[0];
  ((uint4*)dst)[1] = t.u[1];
}

// parallel task logits: 512 threads, 8 chunks of 64 d per (b,e)
__global__ void k_tlog(const int* __restrict__ task_ids, const float* __restrict__ task_emb,
                       const float* __restrict__ gate_w, const float* __restrict__ gate_b,
                       double* __restrict__ tlog) {
  __shared__ double red[64][8];
  int i = threadIdx.x >> 3, ch = threadIdx.x & 7;
  int b = i >> 3, e = i & 7;
  const float* te = task_emb + (size_t)task_ids[b] * D_MODEL;
  double acc = 0.0;
  for (int d = ch * 64; d < ch * 64 + 64; d++)
    acc += (double)te[d] * (double)gate_w[(size_t)(D_MODEL + d) * NEXP + e];
  red[i][ch] = acc;
  __syncthreads();
  if (ch == 0) {
    double s = (double)gate_b[e];
#pragma unroll
    for (int k = 0; k < 8; k++) s += red[i][k];
    tlog[i] = s;
  }
}

// one wave per token: f64 logits, top-2 softmax
__global__ void k_gate(const float* __restrict__ x, const float* __restrict__ gate_w,
                       const double* __restrict__ tlog,
                       float* __restrict__ logits_out,
                       int* __restrict__ toke, float2* __restrict__ tg,
                       float* __restrict__ omega) {
  int gtid = blockIdx.x * blockDim.x + threadIdx.x;
  int t = gtid >> 6;
  int lane = gtid & 63;
  if (t >= TOKENS) return;
  const float* xr = x + (size_t)t * D_MODEL;
  int d0 = lane * 8;
  float4 xa = *(const float4*)(xr + d0);
  float4 xc = *(const float4*)(xr + d0 + 4);
  float xv[8] = {xa.x, xa.y, xa.z, xa.w, xc.x, xc.y, xc.z, xc.w};
  double acc[NEXP];
#pragma unroll
  for (int e = 0; e < NEXP; e++) acc[e] = 0.0;
#pragma unroll
  for (int j = 0; j < 8; j++) {
    const float* gwr = gate_w + (size_t)(d0 + j) * NEXP;
    float4 g0 = *(const float4*)gwr;
    float4 g1 = *(const float4*)(gwr + 4);
    double xd = (double)xv[j];
    acc[0] += xd * (double)g0.x; acc[1] += xd * (double)g0.y;
    acc[2] += xd * (double)g0.z; acc[3] += xd * (double)g0.w;
    acc[4] += xd * (double)g1.x; acc[5] += xd * (double)g1.y;
    acc[6] += xd * (double)g1.z; acc[7] += xd * (double)g1.w;
  }
#pragma unroll
  for (int off = 32; off > 0; off >>= 1) {
#pragma unroll
    for (int e = 0; e < NEXP; e++) acc[e] += __shfl_xor(acc[e], off);
  }
  if (lane == 0) {
    int b = t >> 10;
    double lg[NEXP];
#pragma unroll
    for (int e = 0; e < NEXP; e++) {
      lg[e] = acc[e] + tlog[b * NEXP + e];
      logits_out[(size_t)t * NEXP + e] = (float)lg[e];
    }
    int e0 = 0;
    for (int e = 1; e < NEXP; e++) if (lg[e] > lg[e0]) e0 = e;
    int e1 = (e0 == 0) ? 1 : 0;
    for (int e = 0; e < NEXP; e++) if (e != e0 && lg[e] > lg[e1]) e1 = e;
    double p0 = 1.0 / (1.0 + exp(lg[e1] - lg[e0]));
    float g0f = (float)p0;
    float g1f = (float)(1.0 - p0);
    omega[t] = 1.0f - g0f;
    toke[t] = e0 | (e1 << 8);
    tg[t] = float2{g0f, g1f};
  }
}

__global__ void k_route(const int* __restrict__ toke, const float2* __restrict__ tg,
                        int* __restrict__ counts, int* __restrict__ tokl,
                        float* __restrict__ gatel) {
  __shared__ int lcnt[NEXP];
  __shared__ int lbase[NEXP];
  const int tid = threadIdx.x;
  if (tid < NEXP) lcnt[tid] = 0;
  __syncthreads();
  const int t = blockIdx.x * 256 + tid;
  const int pe = toke[t];
  const int e0 = pe & 0xff, e1 = pe >> 8;
  const float2 g = tg[t];
  const int r0 = atomicAdd(&lcnt[e0], 1);
  const int r1 = atomicAdd(&lcnt[e1], 1);
  __syncthreads();
  if (tid < NEXP) lbase[tid] = atomicAdd(counts + tid, lcnt[tid]);
  __syncthreads();
  int i0 = lbase[e0] + r0;
  tokl[e0 * TOKENS + i0]  = (t << 1);
  gatel[e0 * TOKENS + i0] = g.x;
  int i1 = lbase[e1] + r1;
  tokl[e1 * TOKENS + i1]  = (t << 1) | 1;
  gatel[e1 * TOKENS + i1] = g.y;
}

// fused: row metadata (soff computed locally from cnts) + X gather into xgp.
// Block 0 thread 255 also publishes soff/tmap for the gemms.
__global__ void k_fillgather(const float* __restrict__ x, const int* __restrict__ cnts,
                             const int* __restrict__ tokl, const float* __restrict__ gatel,
                             const float* __restrict__ omega,
                             int* __restrict__ rmeta, float* __restrict__ rgate,
                             int* __restrict__ soff_g, int* __restrict__ tmap,
                             bf16_t* __restrict__ xgp) {
  __shared__ int lmeta[128];
  const int tid = threadIdx.x;
  const int rbase = blockIdx.x * 128;
  int so[8], sp[8];
  {
    int off = TOKENS;
#pragma unroll
    for (int e = 0; e < 8; e++) {
      int c = cnts[e];
      int p = (c + 255) & ~255;
      so[e] = off; sp[e] = p; off += p;
    }
  }
  if (tid < 128) {
    int r = rbase + tid;
    int meta = 3; float g = 0.f;
    if (r < TOKENS) { meta = (r << 2) | 2; g = omega[r]; }
    else {
#pragma unroll
      for (int e = 0; e < 8; e++) {
        if (r >= so[e] && r < so[e] + sp[e]) {
          int i = r - so[e];
          if (i < cnts[e]) {
            int en = tokl[e * TOKENS + i];
            meta = ((en >> 1) << 2) | (en & 1);
            g = gatel[e * TOKENS + i];
          }
          break;
        }
      }
    }
    rmeta[r] = meta; rgate[r] = g; lmeta[tid] = meta;
  }
  if (blockIdx.x == 0 && tid == 255) {
    int n = 0;
    for (int mt = 0; mt < 32; mt++) tmap[n++] = (8 << 8) | mt;
    for (int e = 0; e < 8; e++) {
      soff_g[e] = so[e];
      for (int mt = 0; mt < (sp[e] >> 8); mt++) tmap[n++] = (e << 8) | mt;
    }
    soff_g[8] = 0;
    tmap[128] = n;
  }
  __syncthreads();
#pragma unroll
  for (int it = 0; it < 8; it++) {
    int id = it * 256 + tid;
    int lrow = id >> 4, s = id & 15;
    int meta = lmeta[lrow];
    union { bf16_t h[32]; uint4 u[4]; } t;
    if ((meta & 3) == 3) {
#pragma unroll
      for (int j = 0; j < 4; j++) t.u[j] = uint4{0, 0, 0, 0};
    } else {
      const float* src = x + (size_t)(meta >> 2) * D_MODEL + s * 32;
#pragma unroll
      for (int j = 0; j < 32; j += 4) {
        float4 v = *(const float4*)(src + j);
        t.h[j] = (bf16_t)v.x; t.h[j + 1] = (bf16_t)v.y;
        t.h[j + 2] = (bf16_t)v.z; t.h[j + 3] = (bf16_t)v.w;
      }
    }
    char* dst = (char*)xgp + ((size_t)s * TROWS + rbase + lrow) * 64;
#pragma unroll
    for (int j = 0; j < 4; j++) ((uint4*)dst)[j] = t.u[j];
  }
}

// ============================================================================
// 256x128 / BK=32 GEMM, 4-wave (256-thread) blocks, wave tile 128x64.
// LDS-BW roofline math: wave reads 12 b128 frags (12KB) per kt for 32 MFMA
// -> 384 B/MFMA vs 512 B/MFMA at 64x64 -> shape ceiling 40% MfmaUtil (was
// 30%, measured AT 30%). 8 waves/CU (2 independent blocks, 72KB LDS each)
// keep the LDS pipe fed across barrier tails. acc[8][4]=128 VGPR + frags ~50
// -> ~200 regs, fine at 2 waves/SIMD.
// 3-deep rotation (R5/R7-proven): kt reads set kt%3, stages kt+2 into
// (kt+2)%3; 6 stage loads/thread -> counted vmcnt(6) (never 0 mid-loop);
// trailing lgkmcnt(0) before the barrier for cross-wave WAR safety.
// XOR swizzle slot^=(row>>1)&3 on stage-source + ds_read; LDS dest linear.
// Swapped MFMA operands -> lane holds 4 consecutive out-cols.
// ============================================================================
template <int KT, int NB, int EPI, int NT, int LOG2NT>
__global__ __launch_bounds__(256, 2) void k_gemm(
    const bf16_t* __restrict__ Ab, const bf16_t* __restrict__ wEx,
    const bf16_t* __restrict__ wUn, const float* __restrict__ bEx,
    const float* __restrict__ bUn,
    const int* __restrict__ soff, const int* __restrict__ tmap,
    bf16_t* __restrict__ hpOut,
    const int* __restrict__ rmeta, const float* __restrict__ rgate,
    bf16_t* __restrict__ s0, bf16_t* __restrict__ s1, float* __restrict__ outF) {
  const int wg = blockIdx.x;
  const int xcd = wg & 7, j = wg >> 3;
  const int t = xcd + ((j >> LOG2NT) << 3);     // dense tile index, t%8 == xcd
  const int nt = j & (NT - 1);
  if (t >= tmap[128]) return;
  const int tm = tmap[t];
  const int sec = tm >> 8, mt = tm & 255;

  const int groff = soff[sec];
  const char* Bsec = (const char*)((sec == 8) ? wUn : (wEx + (size_t)sec * KT * NB * 32));
  const float* bias = (sec == 8) ? bUn : (bEx + sec * NB);

  __shared__ char smem[73728];   // A [3][16KB] @0, B [3][8KB] @49152
  const int tid = threadIdx.x;
  const int wave = tid >> 6, lane = tid & 63;
  const int l16 = lane & 15, quad = lane >> 4;
  const int wm = wave >> 1, wn = wave & 1;

  // staging (256 threads): A 16KB region = chunks tid + k*256 (k=0..3);
  // B 8KB = chunks tid, tid+256. chunk c -> (row=c>>2, slot=c&3);
  // source slot = slot ^ ((row>>1)&3)  (invariant under +64-row steps)
  const int r0 = tid >> 2;
  const int ss = (tid & 3) ^ ((tid >> 3) & 3);
  const int grow0 = groff + mt * 256;
  const char* aSrc = (const char*)Ab + (size_t)(grow0 + r0) * 64 + ss * 16;
  const char* bSrc = Bsec + (size_t)(nt * 128 + r0) * 64 + ss * 16;
  char* ldsWA = smem + wave * 1024;
  char* ldsWB = smem + 49152 + wave * 1024;

  // fragment read offsets (swizzled); bRd RELATIVE to B-region base
  const int swz = ((quad ^ ((l16 >> 1) & 3)) << 4);
  const int aRd = (wm * 128 + l16) * 64 + swz;
  const int bRd = (wn * 64 + l16) * 64 + swz;

  f32x4_t acc[8][4];
#pragma unroll
  for (int i = 0; i < 8; i++)
#pragma unroll
    for (int n = 0; n < 4; n++) acc[i][n] = f32x4_t{0.f, 0.f, 0.f, 0.f};

  auto stage = [&](int kt, int set) {
    const char* ga = aSrc + (size_t)kt * ((size_t)TROWS * 64);
    char* la = ldsWA + set * 16384;
    load_lds16(ga, la);
    load_lds16(ga + 4096, la + 4096);
    load_lds16(ga + 8192, la + 8192);
    load_lds16(ga + 12288, la + 12288);
    const char* gb = bSrc + (size_t)kt * ((size_t)NB * 64);
    char* lb = ldsWB + set * 8192;
    load_lds16(gb, lb);
    load_lds16(gb + 4096, lb + 4096);
  };

  // prologue
  stage(0, 0); stage(1, 1);
  asm volatile("s_waitcnt vmcnt(6)" ::: "memory");
  __builtin_amdgcn_s_barrier();

  int rs = 0, ws = 2;
  for (int kt = 0; kt < KT; ++kt) {
    if (kt < KT - 2) stage(kt + 2, ws);
    const char* abase = smem + rs * 16384;
    const char* bbase = smem + 49152 + rs * 8192;
    bf16x8_t Ar[8], Br[4];
#pragma unroll
    for (int f = 0; f < 8; f++) Ar[f] = *(const bf16x8_t*)(abase + aRd + f * 1024);
#pragma unroll
    for (int f = 0; f < 4; f++) Br[f] = *(const bf16x8_t*)(bbase + bRd + f * 1024);
    __builtin_amdgcn_s_setprio(1);
#pragma unroll
    for (int mm = 0; mm < 8; mm++)
#pragma unroll
      for (int n = 0; n < 4; n++)
        acc[mm][n] = mfma_bf16(Br[n], Ar[mm], acc[mm][n]);  // swapped operands
    __builtin_amdgcn_s_setprio(0);
    asm volatile("s_waitcnt lgkmcnt(0)" ::: "memory");   // WAR: reads of rs drained
    if (kt < KT - 2)       asm volatile("s_waitcnt vmcnt(6)" ::: "memory");
    else if (kt == KT - 2) asm volatile("s_waitcnt vmcnt(0)" ::: "memory");
    if (kt < KT - 1) __builtin_amdgcn_s_barrier();
    if (++rs == 3) rs = 0;
    if (++ws == 3) ws = 0;
  }

  // ---- epilogue: lane holds C[row = wm*128+mm*16+l16][col = nt*128+wn*64+n*16+quad*4 .. +3]
  const int colq = wn * 64 + quad * 4;
  float4 bv[4];
#pragma unroll
  for (int n = 0; n < 4; n++)
    bv[n] = *(const float4*)(bias + nt * 128 + colq + n * 16);

  if constexpr (EPI == 0) {
    // bias + gelu -> hp k-slab [slab][TROWS][32], packed 8-B stores
#pragma unroll
    for (int mm = 0; mm < 8; mm++) {
      const int row = grow0 + wm * 128 + mm * 16 + l16;
#pragma unroll
      for (int n = 0; n < 4; n++) {
        float b4[4] = {bv[n].x, bv[n].y, bv[n].z, bv[n].w};
        union { bf16_t h[4]; uint2 u; } t2;
#pragma unroll
        for (int i = 0; i < 4; i++)
          t2.h[i] = (bf16_t)fast_gelu(acc[mm][n][i] + b4[i]);
        char* dst = (char*)hpOut +
            ((size_t)(nt * 4 + wn * 2 + (n >> 1)) * TROWS + row) * 64 +
            (n & 1) * 32 + quad * 8;
        *(uint2*)dst = t2.u;
      }
    }
  } else {
    // +b2, *gate, scatter by slot (each token-slot written exactly once)
#pragma unroll
    for (int mm = 0; mm < 8; mm++) {
      const int grow = grow0 + wm * 128 + mm * 16 + l16;
      const int dbase = nt * 128 + colq;
      if (sec == 8) {
        const float g = rgate[grow];
        float* dst = outF + (size_t)grow * D_MODEL + dbase;
#pragma unroll
        for (int n = 0; n < 4; n++) {
          float b4[4] = {bv[n].x, bv[n].y, bv[n].z, bv[n].w};
          float4 o;
          o.x = (acc[mm][n][0] + b4[0]) * g;
          o.y = (acc[mm][n][1] + b4[1]) * g;
          o.z = (acc[mm][n][2] + b4[2]) * g;
          o.w = (acc[mm][n][3] + b4[3]) * g;
          *(float4*)(dst + n * 16) = o;
        }
      } else {
        const int meta = rmeta[grow];
        const int slot = meta & 3;
        if (slot == 3) continue;
        const float g = rgate[grow];
        bf16_t* dst = (slot ? s1 : s0) + (size_t)(meta >> 2) * D_MODEL + dbase;
#pragma unroll
        for (int n = 0; n < 4; n++) {
          float b4[4] = {bv[n].x, bv[n].y, bv[n].z, bv[n].w};
          union { bf16_t h[4]; uint2 u; } t2;
#pragma unroll
          for (int i = 0; i < 4; i++)
            t2.h[i] = (bf16_t)((acc[mm][n][i] + b4[i]) * g);
          *(uint2*)(dst + n * 16) = t2.u;
        }
      }
    }
  }
}

__global__ void k_combine(const bf16x4_t* __restrict__ s0, const bf16x4_t* __restrict__ s1,
                          float4* __restrict__ out, int n4) {
  int i = blockIdx.x * blockDim.x + threadIdx.x;
  if (i >= n4) return;
  bf16x4_t a = s0[i], b = s1[i];
  float4 o = out[i];
  o.x += (float)a[0] + (float)b[0];
  o.y += (float)a[1] + (float)b[1];
  o.z += (float)a[2] + (float)b[2];
  o.w += (float)a[3] + (float)b[3];
  out[i] = o;
}

extern "C" void kernel_launch(void* const* d_in, const int* in_sizes, int n_in,
                              void* d_out, int out_size, void* d_ws, size_t ws_size,
                              hipStream_t stream) {
  (void)in_sizes; (void)n_in; (void)out_size; (void)ws_size;
  const float* x        = (const float*)d_in[0];
  const int*   task_ids = (const int*)  d_in[1];
  const float* task_emb = (const float*)d_in[2];
  const float* gate_w   = (const float*)d_in[3];
  const float* gate_b   = (const float*)d_in[4];
  const float* w1       = (const float*)d_in[5];
  const float* b1       = (const float*)d_in[6];
  const float* w2       = (const float*)d_in[7];
  const float* b2       = (const float*)d_in[8];
  const float* uw1      = (const float*)d_in[9];
  const float* ub1      = (const float*)d_in[10];
  const float* uw2      = (const float*)d_in[11];
  const float* ub2      = (const float*)d_in[12];

  char* ws = (char*)d_ws;
  bf16_t* w1p   = (bf16_t*)(ws + W1P_OFF);
  bf16_t* uw1p  = (bf16_t*)(ws + UW1P_OFF);
  bf16_t* w2p   = (bf16_t*)(ws + W2P_OFF);
  bf16_t* uw2p  = (bf16_t*)(ws + UW2P_OFF);
  bf16_t* s0    = (bf16_t*)(ws + S0_OFF);
  bf16_t* s1    = (bf16_t*)(ws + S1_OFF);
  int*    cnts  = (int*)   (ws + CNT_OFF);
  int*    tokl  = (int*)   (ws + TOKL_OFF);
  float*  gatel = (float*) (ws + GATEL_OFF);
  float*  omg   = (float*) (ws + OMEGA_OFF);
  double* tlog  = (double*)(ws + TLOG_OFF);
  int*    soff  = (int*)   (ws + SOFF_OFF);
  int*    rmeta = (int*)   (ws + RMETA_OFF);
  float*  rgate = (float*) (ws + RGATE_OFF);
  bf16_t* xgp   = (bf16_t*)(ws + XGP_OFF);
  bf16_t* hp    = (bf16_t*)(ws + HP_OFF);
  int*    toke  = (int*)   (ws + TOKE_OFF);
  float2* tg    = (float2*)(ws + TG_OFF);
  int*    tmap  = (int*)   (ws + TMAP_OFF);

  float* out    = (float*)d_out;
  float* logits = out + (size_t)TOKENS * D_MODEL;

  hipMemsetAsync(cnts, 0, 64, stream);

  k_pack<<<dim3(32, 8, 9), 256, 0, stream>>>(w1, uw1, w1p, uw1p, D_MODEL, D_FF);
  k_pack<<<dim3(8, 32, 9), 256, 0, stream>>>(w2, uw2, w2p, uw2p, D_FF, D_MODEL);
  k_tlog<<<1, 512, 0, stream>>>(task_ids, task_emb, gate_w, gate_b, tlog);
  k_gate<<<dim3(TOKENS / 4), 256, 0, stream>>>(x, gate_w, tlog, logits, toke, tg, omg);
  k_route<<<dim3(TOKENS / 256), 256, 0, stream>>>(toke, tg, cnts, tokl, gatel);
  k_fillgather<<<dim3(TROWS / 128), 256, 0, stream>>>(x, cnts, tokl, gatel, omg,
                                                      rmeta, rgate, soff, tmap, xgp);
  // dense grids: max 104 m-tiles; gemm1: 16 nt of 128; gemm2: 4 nt of 128
  k_gemm<16, D_FF, 0, 16, 4><<<dim3(104 * 16), 256, 0, stream>>>(
      xgp, w1p, uw1p, b1, ub1, soff, tmap, hp,
      nullptr, nullptr, nullptr, nullptr, nullptr);
  k_gemm<64, D_MODEL, 1, 4, 2><<<dim3(104 * 4), 256, 0, stream>>>(
      hp, w2p, uw2p, b2, ub2, soff, tmap, nullptr,
      rmeta, rgate, s0, s1, out);
  const int n4 = TOKENS * D_MODEL / 4;
  k_combine<<<dim3(n4 / 256), 256, 0, stream>>>((const bf16x4_t*)s0, (const bf16x4_t*)s1,
                                                (float4*)out, n4);
}

// Round 9
// 318.719 us; speedup vs baseline: 1.1042x; 1.1042x over previous
//
#include <hip/hip_runtime.h>

#define D_MODEL 512
#define D_FF    2048
#define NEXP    8
#define TOKENS  8192
#define TROWS   26368     // 8192 universal + <=18176 expert slots padded to 256

typedef __bf16 bf16_t;
typedef __attribute__((ext_vector_type(8))) __bf16 bf16x8_t;
typedef __attribute__((ext_vector_type(4))) __bf16 bf16x4_t;
typedef __attribute__((ext_vector_type(4))) float  f32x4_t;

// ---- workspace layout (bytes) ----
#define W1P_OFF    0u            // bf16 [16][2048][32] x8 experts
#define UW1P_OFF   16777216u     // bf16 [16][2048][32]
#define W2P_OFF    18874368u     // bf16 [64][512][32] x8
#define UW2P_OFF   35651584u     // bf16 [64][512][32]
#define CNT_OFF    37748736u     // int[16]
#define TOKL_OFF   37748800u     // int  [8][8192]
#define GATEL_OFF  38010944u     // float[8][8192]
#define OMEGA_OFF  38273088u     // float[8192]
#define TLOG_OFF   38305856u     // double[8][8]
#define SOFF_OFF   38306368u     // int[16]
#define RMETA_OFF  38306496u     // int[TROWS]
#define RGATE_OFF  38411968u     // float[TROWS]
#define XGP_OFF    38517440u     // bf16 [16][TROWS][32]
#define S0_OFF     38517440u     // ALIAS of XGP (xgp dead before gemm2 writes s0/s1)
#define S1_OFF     46906048u     // ALIAS of XGP
#define HP_OFF     65517248u     // bf16 [64][TROWS][32]
#define TOKE_OFF   173516480u    // int[8192]
#define TG_OFF     173549248u    // float2[8192]
#define TMAP_OFF   173614784u    // int[136]

__device__ inline f32x4_t mfma_bf16(bf16x8_t a, bf16x8_t b, f32x4_t c) {
  return __builtin_amdgcn_mfma_f32_16x16x32_bf16(a, b, c, 0, 0, 0);
}

__device__ __forceinline__ void load_lds16(const void* g, void* l) {
  __builtin_amdgcn_global_load_lds(
      (const __attribute__((address_space(1))) unsigned int*)g,
      (__attribute__((address_space(3))) unsigned int*)l, 16, 0, 0);
}

// fast gelu: max abs err ~3e-4 << bf16 quantum
__device__ __forceinline__ float fast_gelu(float x) {
  float z = 0.7978845608f * (x + 0.044715f * x * x * x);
  float u = __expf(2.0f * z);
  float th = (u - 1.0f) * __builtin_amdgcn_rcpf(u + 1.0f);
  return 0.5f * x * (1.0f + th);
}

// merged pack: z 0..8 -> w1/uw1 (R=512,C=2048); z 9..17 -> w2/uw2 (R=2048,C=512)
// in[R][C] f32 -> out[R/32][C][32] bf16, LDS-free, coalesced per-k reads
__global__ void k_packall(const float* __restrict__ w1, const float* __restrict__ uw1,
                          const float* __restrict__ w2, const float* __restrict__ uw2,
                          bf16_t* __restrict__ w1p, bf16_t* __restrict__ uw1p,
                          bf16_t* __restrict__ w2p, bf16_t* __restrict__ uw2p) {
  const int z = blockIdx.z;
  const float* in; bf16_t* out; int R, C, r0, c0;
  if (z < 9) {
    R = D_MODEL; C = D_FF;
    in  = (z < 8) ? w1 + (size_t)z * R * C : uw1;
    out = (z < 8) ? w1p + (size_t)z * R * C : uw1p;
    r0 = blockIdx.y * 64; c0 = blockIdx.x * 64;
  } else {
    R = D_FF; C = D_MODEL;
    int zz = z - 9;
    in  = (zz < 8) ? w2 + (size_t)zz * R * C : uw2;
    out = (zz < 8) ? w2p + (size_t)zz * R * C : uw2p;
    int lid = blockIdx.y * 32 + blockIdx.x;   // 0..255
    r0 = (lid >> 3) * 64; c0 = (lid & 7) * 64;
  }
  int item = threadIdx.x >> 1, jh = threadIdx.x & 1;
  int c = item & 63, s = item >> 6;
  const float* src = in + (size_t)(r0 + s * 32 + jh * 16) * C + (c0 + c);
  union { bf16_t h[16]; uint4 u[2]; } t;
#pragma unroll
  for (int k = 0; k < 16; k++) t.h[k] = (bf16_t)src[(size_t)k * C];
  char* dst = (char*)out + ((size_t)((r0 >> 5) + s) * C + (c0 + c)) * 64 + jh * 32;
  ((uint4*)dst)[0] = t.u[0];
  ((uint4*)dst)[1] = t.u[1];
}

// task logits: 64 blocks (one per (b,e)) x 1 wave; shfl-reduced f64 dot
__global__ void k_tlog(const int* __restrict__ task_ids, const float* __restrict__ task_emb,
                       const float* __restrict__ gate_w, const float* __restrict__ gate_b,
                       double* __restrict__ tlog) {
  const int b = blockIdx.x >> 3, e = blockIdx.x & 7;
  const int lane = threadIdx.x;
  const float* te = task_emb + (size_t)task_ids[b] * D_MODEL;
  double acc = 0.0;
#pragma unroll
  for (int j = 0; j < 8; j++) {
    int d = lane * 8 + j;
    acc += (double)te[d] * (double)gate_w[(size_t)(D_MODEL + d) * NEXP + e];
  }
#pragma unroll
  for (int off = 32; off > 0; off >>= 1) acc += __shfl_xor(acc, off);
  if (lane == 0) tlog[b * NEXP + e] = acc + (double)gate_b[e];
}

// one wave per token: f64 logits, top-2 softmax
__global__ void k_gate(const float* __restrict__ x, const float* __restrict__ gate_w,
                       const double* __restrict__ tlog,
                       float* __restrict__ logits_out,
                       int* __restrict__ toke, float2* __restrict__ tg,
                       float* __restrict__ omega) {
  int gtid = blockIdx.x * blockDim.x + threadIdx.x;
  int t = gtid >> 6;
  int lane = gtid & 63;
  if (t >= TOKENS) return;
  const float* xr = x + (size_t)t * D_MODEL;
  int d0 = lane * 8;
  float4 xa = *(const float4*)(xr + d0);
  float4 xc = *(const float4*)(xr + d0 + 4);
  float xv[8] = {xa.x, xa.y, xa.z, xa.w, xc.x, xc.y, xc.z, xc.w};
  double acc[NEXP];
#pragma unroll
  for (int e = 0; e < NEXP; e++) acc[e] = 0.0;
#pragma unroll
  for (int j = 0; j < 8; j++) {
    const float* gwr = gate_w + (size_t)(d0 + j) * NEXP;
    float4 g0 = *(const float4*)gwr;
    float4 g1 = *(const float4*)(gwr + 4);
    double xd = (double)xv[j];
    acc[0] += xd * (double)g0.x; acc[1] += xd * (double)g0.y;
    acc[2] += xd * (double)g0.z; acc[3] += xd * (double)g0.w;
    acc[4] += xd * (double)g1.x; acc[5] += xd * (double)g1.y;
    acc[6] += xd * (double)g1.z; acc[7] += xd * (double)g1.w;
  }
#pragma unroll
  for (int off = 32; off > 0; off >>= 1) {
#pragma unroll
    for (int e = 0; e < NEXP; e++) acc[e] += __shfl_xor(acc[e], off);
  }
  if (lane == 0) {
    int b = t >> 10;
    double lg[NEXP];
#pragma unroll
    for (int e = 0; e < NEXP; e++) {
      lg[e] = acc[e] + tlog[b * NEXP + e];
      logits_out[(size_t)t * NEXP + e] = (float)lg[e];
    }
    int e0 = 0;
    for (int e = 1; e < NEXP; e++) if (lg[e] > lg[e0]) e0 = e;
    int e1 = (e0 == 0) ? 1 : 0;
    for (int e = 0; e < NEXP; e++) if (e != e0 && lg[e] > lg[e1]) e1 = e;
    double p0 = 1.0 / (1.0 + exp(lg[e1] - lg[e0]));
    float g0f = (float)p0;
    float g1f = (float)(1.0 - p0);
    omega[t] = 1.0f - g0f;
    toke[t] = e0 | (e1 << 8);
    tg[t] = float2{g0f, g1f};
  }
}

__global__ void k_route(const int* __restrict__ toke, const float2* __restrict__ tg,
                        int* __restrict__ counts, int* __restrict__ tokl,
                        float* __restrict__ gatel) {
  __shared__ int lcnt[NEXP];
  __shared__ int lbase[NEXP];
  const int tid = threadIdx.x;
  if (tid < NEXP) lcnt[tid] = 0;
  __syncthreads();
  const int t = blockIdx.x * 256 + tid;
  const int pe = toke[t];
  const int e0 = pe & 0xff, e1 = pe >> 8;
  const float2 g = tg[t];
  const int r0 = atomicAdd(&lcnt[e0], 1);
  const int r1 = atomicAdd(&lcnt[e1], 1);
  __syncthreads();
  if (tid < NEXP) lbase[tid] = atomicAdd(counts + tid, lcnt[tid]);
  __syncthreads();
  int i0 = lbase[e0] + r0;
  tokl[e0 * TOKENS + i0]  = (t << 1);
  gatel[e0 * TOKENS + i0] = g.x;
  int i1 = lbase[e1] + r1;
  tokl[e1 * TOKENS + i1]  = (t << 1) | 1;
  gatel[e1 * TOKENS + i1] = g.y;
}

// fused: row metadata (soff computed locally from cnts) + X gather into xgp.
// Block 0 thread 255 also publishes soff/tmap for the gemms.
__global__ void k_fillgather(const float* __restrict__ x, const int* __restrict__ cnts,
                             const int* __restrict__ tokl, const float* __restrict__ gatel,
                             const float* __restrict__ omega,
                             int* __restrict__ rmeta, float* __restrict__ rgate,
                             int* __restrict__ soff_g, int* __restrict__ tmap,
                             bf16_t* __restrict__ xgp) {
  __shared__ int lmeta[128];
  const int tid = threadIdx.x;
  const int rbase = blockIdx.x * 128;
  int so[8], sp[8];
  {
    int off = TOKENS;
#pragma unroll
    for (int e = 0; e < 8; e++) {
      int c = cnts[e];
      int p = (c + 255) & ~255;
      so[e] = off; sp[e] = p; off += p;
    }
  }
  if (tid < 128) {
    int r = rbase + tid;
    int meta = 3; float g = 0.f;
    if (r < TOKENS) { meta = (r << 2) | 2; g = omega[r]; }
    else {
#pragma unroll
      for (int e = 0; e < 8; e++) {
        if (r >= so[e] && r < so[e] + sp[e]) {
          int i = r - so[e];
          if (i < cnts[e]) {
            int en = tokl[e * TOKENS + i];
            meta = ((en >> 1) << 2) | (en & 1);
            g = gatel[e * TOKENS + i];
          }
          break;
        }
      }
    }
    rmeta[r] = meta; rgate[r] = g; lmeta[tid] = meta;
  }
  if (blockIdx.x == 0 && tid == 255) {
    int n = 0;
    for (int mt = 0; mt < 32; mt++) tmap[n++] = (8 << 8) | mt;
    for (int e = 0; e < 8; e++) {
      soff_g[e] = so[e];
      for (int mt = 0; mt < (sp[e] >> 8); mt++) tmap[n++] = (e << 8) | mt;
    }
    soff_g[8] = 0;
    tmap[128] = n;
  }
  __syncthreads();
#pragma unroll
  for (int it = 0; it < 8; it++) {
    int id = it * 256 + tid;
    int lrow = id >> 4, s = id & 15;
    int meta = lmeta[lrow];
    union { bf16_t h[32]; uint4 u[4]; } t;
    if ((meta & 3) == 3) {
#pragma unroll
      for (int j = 0; j < 4; j++) t.u[j] = uint4{0, 0, 0, 0};
    } else {
      const float* src = x + (size_t)(meta >> 2) * D_MODEL + s * 32;
#pragma unroll
      for (int j = 0; j < 32; j += 4) {
        float4 v = *(const float4*)(src + j);
        t.h[j] = (bf16_t)v.x; t.h[j + 1] = (bf16_t)v.y;
        t.h[j + 2] = (bf16_t)v.z; t.h[j + 3] = (bf16_t)v.w;
      }
    }
    char* dst = (char*)xgp + ((size_t)s * TROWS + rbase + lrow) * 64;
#pragma unroll
    for (int j = 0; j < 4; j++) ((uint4*)dst)[j] = t.u[j];
  }
}

// ============================================================================
// 256x128 / BK=32 / 8-wave / 72-KiB-LDS GEMM, 2 blocks per CU — R7-proven
// config (78 us, MfmaUtil 29.5% == its LDS-BW roofline at ~112 B/cy/CU).
// R8's 128x64 wave-tile experiment (shape ceiling 36-41%) regressed to 24%:
// 8 waves/CU cannot cover LDS latency + barrier tails. Reverted verbatim.
// 3-deep rotation: kt reads set kt%3, stages kt+2 into (kt+2)%3; counted
// vmcnt(3) (never 0 mid-loop); trailing lgkmcnt(0) before the barrier for
// cross-wave WAR safety. XOR swizzle slot^=(row>>1)&3 on stage-source +
// ds_read; LDS dest linear. Swapped MFMA operands -> packed epilogue stores.
// ============================================================================
template <int KT, int NB, int EPI, int NT, int LOG2NT>
__global__ __launch_bounds__(512, 4) void k_gemm(
    const bf16_t* __restrict__ Ab, const bf16_t* __restrict__ wEx,
    const bf16_t* __restrict__ wUn, const float* __restrict__ bEx,
    const float* __restrict__ bUn,
    const int* __restrict__ soff, const int* __restrict__ tmap,
    bf16_t* __restrict__ hpOut,
    const int* __restrict__ rmeta, const float* __restrict__ rgate,
    bf16_t* __restrict__ s0, bf16_t* __restrict__ s1, float* __restrict__ outF) {
  const int wg = blockIdx.x;
  const int xcd = wg & 7, j = wg >> 3;
  const int t = xcd + ((j >> LOG2NT) << 3);     // dense tile index, t%8 == xcd
  const int nt = j & (NT - 1);
  if (t >= tmap[128]) return;
  const int tm = tmap[t];
  const int sec = tm >> 8, mt = tm & 255;

  const int groff = soff[sec];
  const char* Bsec = (const char*)((sec == 8) ? wUn : (wEx + (size_t)sec * KT * NB * 32));
  const float* bias = (sec == 8) ? bUn : (bEx + sec * NB);

  __shared__ char smem[73728];
  const int tid = threadIdx.x;
  const int wave = tid >> 6, lane = tid & 63;
  const int l16 = lane & 15, quad = lane >> 4;
  const int wm = wave >> 1, wn = wave & 1;

  const int r0 = tid >> 2;
  const int ss = (tid & 3) ^ ((tid >> 3) & 3);
  const int grow0 = groff + mt * 256;
  const char* aSrc = (const char*)Ab + (size_t)(grow0 + r0) * 64 + ss * 16;
  const char* bSrc = Bsec + (size_t)(nt * 128 + r0) * 64 + ss * 16;
  char* ldsWA = smem + wave * 1024;
  char* ldsWB = smem + 49152 + wave * 1024;

  const int swz = ((quad ^ ((l16 >> 1) & 3)) << 4);
  const int aRd = (wm * 64 + l16) * 64 + swz;
  const int bRd = (wn * 64 + l16) * 64 + swz;

  f32x4_t acc[4][4];
#pragma unroll
  for (int i = 0; i < 4; i++)
#pragma unroll
    for (int n = 0; n < 4; n++) acc[i][n] = f32x4_t{0.f, 0.f, 0.f, 0.f};

  auto stage = [&](int kt, int set) {
    const char* ga = aSrc + (size_t)kt * ((size_t)TROWS * 64);
    char* la = ldsWA + set * 16384;
    load_lds16(ga, la);
    load_lds16(ga + 8192, la + 8192);
    load_lds16(bSrc + (size_t)kt * ((size_t)NB * 64), ldsWB + set * 8192);
  };

  // prologue
  stage(0, 0); stage(1, 1);
  asm volatile("s_waitcnt vmcnt(3)" ::: "memory");
  __builtin_amdgcn_s_barrier();

  int rs = 0, ws = 2;
  for (int kt = 0; kt < KT; ++kt) {
    if (kt < KT - 2) stage(kt + 2, ws);
    const char* abase = smem + rs * 16384;
    const char* bbase = smem + 49152 + rs * 8192;
    bf16x8_t Ar[4], Br[4];
#pragma unroll
    for (int f = 0; f < 4; f++) Ar[f] = *(const bf16x8_t*)(abase + aRd + f * 1024);
#pragma unroll
    for (int f = 0; f < 4; f++) Br[f] = *(const bf16x8_t*)(bbase + bRd + f * 1024);
    __builtin_amdgcn_s_setprio(1);
#pragma unroll
    for (int mm = 0; mm < 4; mm++)
#pragma unroll
      for (int n = 0; n < 4; n++)
        acc[mm][n] = mfma_bf16(Br[n], Ar[mm], acc[mm][n]);  // swapped operands
    __builtin_amdgcn_s_setprio(0);
    asm volatile("s_waitcnt lgkmcnt(0)" ::: "memory");   // WAR: reads of rs drained
    if (kt < KT - 2)       asm volatile("s_waitcnt vmcnt(3)" ::: "memory");
    else if (kt == KT - 2) asm volatile("s_waitcnt vmcnt(0)" ::: "memory");
    if (kt < KT - 1) __builtin_amdgcn_s_barrier();
    if (++rs == 3) rs = 0;
    if (++ws == 3) ws = 0;
  }

  // ---- epilogue: lane holds C[row = wm*64+mm*16+l16][col = nt*128+wn*64+n*16+quad*4 .. +3]
  const int colq = wn * 64 + quad * 4;
  float4 bv[4];
#pragma unroll
  for (int n = 0; n < 4; n++)
    bv[n] = *(const float4*)(bias + nt * 128 + colq + n * 16);

  if constexpr (EPI == 0) {
#pragma unroll
    for (int mm = 0; mm < 4; mm++) {
      const int row = grow0 + wm * 64 + mm * 16 + l16;
#pragma unroll
      for (int n = 0; n < 4; n++) {
        float b4[4] = {bv[n].x, bv[n].y, bv[n].z, bv[n].w};
        union { bf16_t h[4]; uint2 u; } t2;
#pragma unroll
        for (int i = 0; i < 4; i++)
          t2.h[i] = (bf16_t)fast_gelu(acc[mm][n][i] + b4[i]);
        char* dst = (char*)hpOut +
            ((size_t)(nt * 4 + wn * 2 + (n >> 1)) * TROWS + row) * 64 +
            (n & 1) * 32 + quad * 8;
        *(uint2*)dst = t2.u;
      }
    }
  } else {
#pragma unroll
    for (int mm = 0; mm < 4; mm++) {
      const int grow = grow0 + wm * 64 + mm * 16 + l16;
      const int dbase = nt * 128 + colq;
      if (sec == 8) {
        const float g = rgate[grow];
        float* dst = outF + (size_t)grow * D_MODEL + dbase;
#pragma unroll
        for (int n = 0; n < 4; n++) {
          float b4[4] = {bv[n].x, bv[n].y, bv[n].z, bv[n].w};
          float4 o;
          o.x = (acc[mm][n][0] + b4[0]) * g;
          o.y = (acc[mm][n][1] + b4[1]) * g;
          o.z = (acc[mm][n][2] + b4[2]) * g;
          o.w = (acc[mm][n][3] + b4[3]) * g;
          *(float4*)(dst + n * 16) = o;
        }
      } else {
        const int meta = rmeta[grow];
        const int slot = meta & 3;
        if (slot == 3) continue;
        const float g = rgate[grow];
        bf16_t* dst = (slot ? s1 : s0) + (size_t)(meta >> 2) * D_MODEL + dbase;
#pragma unroll
        for (int n = 0; n < 4; n++) {
          float b4[4] = {bv[n].x, bv[n].y, bv[n].z, bv[n].w};
          union { bf16_t h[4]; uint2 u; } t2;
#pragma unroll
          for (int i = 0; i < 4; i++)
            t2.h[i] = (bf16_t)((acc[mm][n][i] + b4[i]) * g);
          *(uint2*)(dst + n * 16) = t2.u;
        }
      }
    }
  }
}

__global__ void k_combine(const bf16x4_t* __restrict__ s0, const bf16x4_t* __restrict__ s1,
                          float4* __restrict__ out, int n4) {
  int i = blockIdx.x * blockDim.x + threadIdx.x;
  if (i >= n4) return;
  bf16x4_t a = s0[i], b = s1[i];
  float4 o = out[i];
  o.x += (float)a[0] + (float)b[0];
  o.y += (float)a[1] + (float)b[1];
  o.z += (float)a[2] + (float)b[2];
  o.w += (float)a[3] + (float)b[3];
  out[i] = o;
}

extern "C" void kernel_launch(void* const* d_in, const int* in_sizes, int n_in,
                              void* d_out, int out_size, void* d_ws, size_t ws_size,
                              hipStream_t stream) {
  (void)in_sizes; (void)n_in; (void)out_size; (void)ws_size;
  const float* x        = (const float*)d_in[0];
  const int*   task_ids = (const int*)  d_in[1];
  const float* task_emb = (const float*)d_in[2];
  const float* gate_w   = (const float*)d_in[3];
  const float* gate_b   = (const float*)d_in[4];
  const float* w1       = (const float*)d_in[5];
  const float* b1       = (const float*)d_in[6];
  const float* w2       = (const float*)d_in[7];
  const float* b2       = (const float*)d_in[8];
  const float* uw1      = (const float*)d_in[9];
  const float* ub1      = (const float*)d_in[10];
  const float* uw2      = (const float*)d_in[11];
  const float* ub2      = (const float*)d_in[12];

  char* ws = (char*)d_ws;
  bf16_t* w1p   = (bf16_t*)(ws + W1P_OFF);
  bf16_t* uw1p  = (bf16_t*)(ws + UW1P_OFF);
  bf16_t* w2p   = (bf16_t*)(ws + W2P_OFF);
  bf16_t* uw2p  = (bf16_t*)(ws + UW2P_OFF);
  bf16_t* s0    = (bf16_t*)(ws + S0_OFF);
  bf16_t* s1    = (bf16_t*)(ws + S1_OFF);
  int*    cnts  = (int*)   (ws + CNT_OFF);
  int*    tokl  = (int*)   (ws + TOKL_OFF);
  float*  gatel = (float*) (ws + GATEL_OFF);
  float*  omg   = (float*) (ws + OMEGA_OFF);
  double* tlog  = (double*)(ws + TLOG_OFF);
  int*    soff  = (int*)   (ws + SOFF_OFF);
  int*    rmeta = (int*)   (ws + RMETA_OFF);
  float*  rgate = (float*) (ws + RGATE_OFF);
  bf16_t* xgp   = (bf16_t*)(ws + XGP_OFF);
  bf16_t* hp    = (bf16_t*)(ws + HP_OFF);
  int*    toke  = (int*)   (ws + TOKE_OFF);
  float2* tg    = (float2*)(ws + TG_OFF);
  int*    tmap  = (int*)   (ws + TMAP_OFF);

  float* out    = (float*)d_out;
  float* logits = out + (size_t)TOKENS * D_MODEL;

  hipMemsetAsync(cnts, 0, 64, stream);

  k_packall<<<dim3(32, 8, 18), 256, 0, stream>>>(w1, uw1, w2, uw2, w1p, uw1p, w2p, uw2p);
  k_tlog<<<dim3(64), 64, 0, stream>>>(task_ids, task_emb, gate_w, gate_b, tlog);
  k_gate<<<dim3(TOKENS / 4), 256, 0, stream>>>(x, gate_w, tlog, logits, toke, tg, omg);
  k_route<<<dim3(TOKENS / 256), 256, 0, stream>>>(toke, tg, cnts, tokl, gatel);
  k_fillgather<<<dim3(TROWS / 128), 256, 0, stream>>>(x, cnts, tokl, gatel, omg,
                                                      rmeta, rgate, soff, tmap, xgp);
  // dense grids: max 104 m-tiles; gemm1: 16 nt of 128; gemm2: 4 nt of 128
  k_gemm<16, D_FF, 0, 16, 4><<<dim3(104 * 16), 512, 0, stream>>>(
      xgp, w1p, uw1p, b1, ub1, soff, tmap, hp,
      nullptr, nullptr, nullptr, nullptr, nullptr);
  k_gemm<64, D_MODEL, 1, 4, 2><<<dim3(104 * 4), 512, 0, stream>>>(
      hp, w2p, uw2p, b2, ub2, soff, tmap, nullptr,
      rmeta, rgate, s0, s1, out);
  const int n4 = TOKENS * D_MODEL / 4;
  k_combine<<<dim3(n4 / 256), 256, 0, stream>>>((const bf16x4_t*)s0, (const bf16x4_t*)s1,
                                                (float4*)out, n4);
}